// Round 12
// baseline (819.915 us; speedup 1.0000x reference)
//
#include <hip/hip_runtime.h>
#include <hip/hip_fp16.h>

#define HDIM 32
#define IN_DIM 128
#define NEG_SLOPE 0.2f
#define NPB 128            // nodes per coarse bucket (power of 2)
#define NPB_SHIFT 7
#define MAXB 1024          // max buckets (B = ceil(N/128) = 782)
#define CHUNK 8192         // edges per chunk block
#define CAP 4096           // max records per bucket for LDS sort fast path
#define DBINS 128          // degree bins for load-balance sort (clamp)

typedef _Float16 half8  __attribute__((ext_vector_type(8)));
typedef _Float16 half4v __attribute__((ext_vector_type(4)));
typedef float    floatx4 __attribute__((ext_vector_type(4)));

__device__ __forceinline__ float leaky(float e) {
    return (e >= 0.f) ? e : NEG_SLOPE * e;
}

__device__ __forceinline__ float2 h2f(unsigned int u) {
    __half2 h = *reinterpret_cast<__half2*>(&u);
    return __half22float2(h);
}

// ------------- MFMA GEMM: h = x@W fp16 out (no es/ed epilogue) -------------

template<int K>
__global__ __launch_bounds__(256) void gemm_mfma(
    const float* __restrict__ x, const float* __restrict__ W,
    __half* __restrict__ h, int N)
{
    constexpr int KP = K + 8;                 // +8 halves pad -> 2-way conflicts only
    __shared__ _Float16 xs[64 * KP];
    __shared__ _Float16 Wt[32 * KP];          // Wt[n][k] = W[k][n]
    const int tid = threadIdx.x;
    for (int i = tid; i < K * 32; i += 256) {
        int k = i >> 5, n = i & 31;
        Wt[n * KP + k] = (_Float16)W[i];
    }
    const int lane = tid & 63;
    const int wave = tid >> 6;                // 0..3
    const int m16  = lane & 15;
    const int quad = lane >> 4;               // 0..3

    const int ntiles = (N + 63) >> 6;
    for (int tile = blockIdx.x; tile < ntiles; tile += gridDim.x) {
        const int row0 = tile << 6;
        __syncthreads();
        for (int i = tid; i < 64 * (K / 4); i += 256) {
            int r  = i / (K / 4);
            int c4 = i % (K / 4);
            float4 v = (row0 + r < N) ? ((const float4*)x)[(size_t)(row0 + r) * (K / 4) + c4]
                                      : make_float4(0.f, 0.f, 0.f, 0.f);
            half4v hv = { (_Float16)v.x, (_Float16)v.y, (_Float16)v.z, (_Float16)v.w };
            *(half4v*)&xs[r * KP + c4 * 4] = hv;
        }
        __syncthreads();
        floatx4 acc0 = {0.f, 0.f, 0.f, 0.f}, acc1 = {0.f, 0.f, 0.f, 0.f};
        const int rbase = wave * 16;
        #pragma unroll
        for (int kt = 0; kt < K / 32; kt++) {
            half8 a  = *(half8*)&xs[(rbase + m16) * KP + kt * 32 + quad * 8];
            half8 b0 = *(half8*)&Wt[m16 * KP + kt * 32 + quad * 8];
            half8 b1 = *(half8*)&Wt[(m16 + 16) * KP + kt * 32 + quad * 8];
            acc0 = __builtin_amdgcn_mfma_f32_16x16x32_f16(a, b0, acc0, 0, 0, 0);
            acc1 = __builtin_amdgcn_mfma_f32_16x16x32_f16(a, b1, acc1, 0, 0, 0);
        }
        #pragma unroll
        for (int r = 0; r < 4; r++) {
            int row = row0 + rbase + quad * 4 + r;
            if (row < N) {
                h[(size_t)row * HDIM + m16]      = __float2half(acc0[r]);
                h[(size_t)row * HDIM + m16 + 16] = __float2half(acc1[r]);
            }
        }
    }
}

// ---------------- Two-level CSR build (once per call) ----------------

__global__ __launch_bounds__(256) void chunk_hist(
    const int* __restrict__ dsts, int E, int B, int* __restrict__ cnt2D)
{
    __shared__ int hist[MAXB];
    const int blk = blockIdx.x;
    for (int i = threadIdx.x; i < B; i += 256) hist[i] = 0;
    __syncthreads();
    const int e0 = blk * CHUNK;
    for (int i = threadIdx.x; i < CHUNK; i += 256) {
        int e = e0 + i;
        if (e < E) atomicAdd(&hist[dsts[e] >> NPB_SHIFT], 1);
    }
    __syncthreads();
    for (int i = threadIdx.x; i < B; i += 256) cnt2D[(size_t)blk * B + i] = hist[i];
}

__global__ __launch_bounds__(256) void chunk_scan(
    const int* __restrict__ cnt2D, int NBLK, int B,
    int* __restrict__ off2D, int* __restrict__ bcnt)
{
    __shared__ int s[256];
    const int b = blockIdx.x, t = threadIdx.x;
    int v = (t < NBLK) ? cnt2D[(size_t)t * B + b] : 0;
    s[t] = v;
    __syncthreads();
    for (int off = 1; off < 256; off <<= 1) {
        int add = (t >= off) ? s[t - off] : 0;
        __syncthreads();
        s[t] += add;
        __syncthreads();
    }
    if (t < NBLK) off2D[(size_t)t * B + b] = s[t] - v;
    if (t == 255) bcnt[b] = s[255];
}

__global__ __launch_bounds__(1024) void bucket_scan(
    const int* __restrict__ bcnt, int B, int E,
    int* __restrict__ bstart, int* __restrict__ rowptr, int N)
{
    __shared__ int s[1024];
    const int t = threadIdx.x;
    int v = (t < B) ? bcnt[t] : 0;
    s[t] = v;
    __syncthreads();
    for (int off = 1; off < 1024; off <<= 1) {
        int add = (t >= off) ? s[t - off] : 0;
        __syncthreads();
        s[t] += add;
        __syncthreads();
    }
    if (t < B) bstart[t] = s[t] - v;
    if (t == 0) { bstart[B] = E; rowptr[N] = E; }
}

__global__ __launch_bounds__(256) void pair_scatter2(
    const int* __restrict__ srcs, const int* __restrict__ dsts, int E, int B,
    const int* __restrict__ off2D, const int* __restrict__ bstart,
    int* __restrict__ pairs)
{
    __shared__ int cur[MAXB];
    const int blk = blockIdx.x;
    for (int i = threadIdx.x; i < B; i += 256)
        cur[i] = bstart[i] + off2D[(size_t)blk * B + i];
    __syncthreads();
    const int e0 = blk * CHUNK;
    for (int i = threadIdx.x; i < CHUNK; i += 256) {
        int e = e0 + i;
        if (e < E) {
            int s = srcs[e], d = dsts[e];
            int pos = atomicAdd(&cur[d >> NPB_SHIFT], 1);
            pairs[pos] = (s << NPB_SHIFT) | (d & (NPB - 1));
        }
    }
}

__global__ __launch_bounds__(256) void bucket_sort(
    const int* __restrict__ pairs, const int* __restrict__ bstart,
    int* __restrict__ rowptr, int* __restrict__ csrsrc, int N)
{
    __shared__ int ldeg[NPB];
    __shared__ int lex[NPB];
    __shared__ int recs[CAP];
    __shared__ int sorted[CAP];
    const int b = blockIdx.x, t = threadIdx.x;
    const int p0 = bstart[b], p1 = bstart[b + 1];
    const int cnt = p1 - p0;
    if (t < NPB) ldeg[t] = 0;
    __syncthreads();
    for (int i = t; i < cnt; i += 256) {
        int r = pairs[p0 + i];
        atomicAdd(&ldeg[r & (NPB - 1)], 1);
        if (i < CAP) recs[i] = r;
    }
    __syncthreads();
    if (t < NPB) lex[t] = ldeg[t];
    __syncthreads();
    for (int off = 1; off < NPB; off <<= 1) {
        int add = (t >= off && t < NPB) ? lex[t - off] : 0;
        __syncthreads();
        if (t < NPB) lex[t] += add;
        __syncthreads();
    }
    const int node0 = b * NPB;
    if (t < NPB) {
        int excl = lex[t] - ldeg[t];
        if (node0 + t < N) rowptr[node0 + t] = p0 + excl;
        ldeg[t] = excl;
    }
    __syncthreads();
    if (cnt <= CAP) {
        for (int i = t; i < cnt; i += 256) {
            int r = recs[i];
            int pos = atomicAdd(&ldeg[r & (NPB - 1)], 1);
            sorted[pos] = r >> NPB_SHIFT;
        }
        __syncthreads();
        for (int i = t; i < cnt; i += 256) csrsrc[p0 + i] = sorted[i];
    } else {
        for (int i = t; i < cnt; i += 256) {
            int r = pairs[p0 + i];
            int pos = atomicAdd(&ldeg[r & (NPB - 1)], 1);
            csrsrc[p0 + pos] = r >> NPB_SHIFT;
        }
    }
}

// ------------- Degree-sort permutation (load balance, once per call) -------

__global__ __launch_bounds__(256) void deg_hist(
    const int* __restrict__ rowptr, int N, int* __restrict__ dhist)
{
    int i = blockIdx.x * 256 + threadIdx.x;
    if (i < N) {
        int d = rowptr[i + 1] - rowptr[i];
        if (d > DBINS - 1) d = DBINS - 1;
        atomicAdd(&dhist[d], 1);
    }
}

__global__ __launch_bounds__(DBINS) void deg_scan(
    const int* __restrict__ dhist, int* __restrict__ dcur)
{
    __shared__ int s[DBINS];
    int t = threadIdx.x;
    int v = dhist[t];
    s[t] = v;
    __syncthreads();
    for (int off = 1; off < DBINS; off <<= 1) {
        int add = (t >= off) ? s[t - off] : 0;
        __syncthreads();
        s[t] += add;
        __syncthreads();
    }
    dcur[t] = s[t] - v;
}

__global__ __launch_bounds__(256) void deg_scatter(
    const int* __restrict__ rowptr, int N,
    int* __restrict__ dcur, int* __restrict__ perm)
{
    int i = blockIdx.x * 256 + threadIdx.x;
    if (i < N) {
        int d = rowptr[i + 1] - rowptr[i];
        if (d > DBINS - 1) d = DBINS - 1;
        int pos = atomicAdd(&dcur[d], 1);
        perm[pos] = i;
    }
}

// -------- Aggregation: 4 lanes/node, degree-sorted perm, in-register es/ed --

__global__ __launch_bounds__(256) void agg6(
    const __half* __restrict__ h,
    const int* __restrict__ rowptr, const int* __restrict__ csrsrc,
    const int* __restrict__ perm,
    const float* __restrict__ a_s, const float* __restrict__ a_d,
    const float* __restrict__ b, float* __restrict__ out, int N)
{
    const int gid = blockIdx.x * 256 + threadIdx.x;
    const int gi  = gid >> 2;
    const int l   = threadIdx.x & 3;
    if (gi >= N) return;
    const int node = perm[gi];

    const int e0 = rowptr[node];
    const int e1 = rowptr[node + 1];
    const uint4* __restrict__ h16 = (const uint4*)h;

    float asf[8], adf[8];
    #pragma unroll
    for (int i = 0; i < 8; i++) { asf[i] = a_s[l * 8 + i]; adf[i] = a_d[l * 8 + i]; }

    // own row: self es (dsl) and ed_i (edi); row kept for self-loop accumulate
    uint4 uself = h16[(size_t)node * 4 + l];
    float2 g0 = h2f(uself.x), g1 = h2f(uself.y), g2 = h2f(uself.z), g3 = h2f(uself.w);
    float dsl = asf[0]*g0.x + asf[1]*g0.y + asf[2]*g1.x + asf[3]*g1.y
              + asf[4]*g2.x + asf[5]*g2.y + asf[6]*g3.x + asf[7]*g3.y;
    float ddl = adf[0]*g0.x + adf[1]*g0.y + adf[2]*g1.x + adf[3]*g1.y
              + adf[4]*g2.x + adf[5]*g2.y + adf[6]*g3.x + adf[7]*g3.y;
    dsl += __shfl_xor(dsl, 1); dsl += __shfl_xor(dsl, 2);
    ddl += __shfl_xor(ddl, 1); ddl += __shfl_xor(ddl, 2);
    const float edi = ddl;

    float a0=0.f,a1=0.f,a2=0.f,a3=0.f,a4=0.f,a5=0.f,a6=0.f,a7=0.f,den=0.f;

    int e = e0;
    for (; e + 8 <= e1; e += 8) {
        int s[8]; uint4 u[8];
        #pragma unroll
        for (int j = 0; j < 8; j++) s[j] = csrsrc[e + j];
        #pragma unroll
        for (int j = 0; j < 8; j++) u[j] = h16[(size_t)s[j] * 4 + l];
        #pragma unroll
        for (int j = 0; j < 8; j++) {
            float2 f0 = h2f(u[j].x), f1 = h2f(u[j].y), f2 = h2f(u[j].z), f3 = h2f(u[j].w);
            float dot = asf[0]*f0.x + asf[1]*f0.y + asf[2]*f1.x + asf[3]*f1.y
                      + asf[4]*f2.x + asf[5]*f2.y + asf[6]*f3.x + asf[7]*f3.y;
            dot += __shfl_xor(dot, 1);
            dot += __shfl_xor(dot, 2);
            float w = __expf(leaky(dot + edi));
            den += w;
            a0 += w*f0.x; a1 += w*f0.y; a2 += w*f1.x; a3 += w*f1.y;
            a4 += w*f2.x; a5 += w*f2.y; a6 += w*f3.x; a7 += w*f3.y;
        }
    }
    for (; e < e1; e++) {
        int s = csrsrc[e];
        uint4 u = h16[(size_t)s * 4 + l];
        float2 f0 = h2f(u.x), f1 = h2f(u.y), f2 = h2f(u.z), f3 = h2f(u.w);
        float dot = asf[0]*f0.x + asf[1]*f0.y + asf[2]*f1.x + asf[3]*f1.y
                  + asf[4]*f2.x + asf[5]*f2.y + asf[6]*f3.x + asf[7]*f3.y;
        dot += __shfl_xor(dot, 1);
        dot += __shfl_xor(dot, 2);
        float w = __expf(leaky(dot + edi));
        den += w;
        a0 += w*f0.x; a1 += w*f0.y; a2 += w*f1.x; a3 += w*f1.y;
        a4 += w*f2.x; a5 += w*f2.y; a6 += w*f3.x; a7 += w*f3.y;
    }
    {   // self-loop (row already in registers)
        float w = __expf(leaky(dsl + edi));
        den += w;
        a0 += w*g0.x; a1 += w*g0.y; a2 += w*g1.x; a3 += w*g1.y;
        a4 += w*g2.x; a5 += w*g2.y; a6 += w*g3.x; a7 += w*g3.y;
    }

    const float4* b4 = (const float4*)b;
    float4 bv0 = b4[2*l], bv1 = b4[2*l + 1];
    float inv = 1.f / den;
    float4 o0, o1;
    o0.x = a0*inv + bv0.x; o0.y = a1*inv + bv0.y; o0.z = a2*inv + bv0.z; o0.w = a3*inv + bv0.w;
    o1.x = a4*inv + bv1.x; o1.y = a5*inv + bv1.y; o1.z = a6*inv + bv1.z; o1.w = a7*inv + bv1.w;
    ((float4*)out)[(size_t)node*8 + 2*l]     = o0;
    ((float4*)out)[(size_t)node*8 + 2*l + 1] = o1;
}

// -------- Pool: one 64-lane wave per graph (batch sorted, binary search) ---

__global__ __launch_bounds__(256) void pool_graph(
    const float* __restrict__ x, const int* __restrict__ batch,
    float* __restrict__ out, int N, int G)
{
    const int g = (blockIdx.x * 256 + threadIdx.x) >> 6;   // wave id = graph id
    if (g >= G) return;
    const int lane = threadIdx.x & 63;
    const int feat = lane & 31;
    const int half = lane >> 5;

    int lo = 0, hi = N;
    while (lo < hi) { int mid = (lo + hi) >> 1; if (batch[mid] < g) lo = mid + 1; else hi = mid; }
    const int start = lo;
    int lo2 = start, hi2 = N;
    while (lo2 < hi2) { int mid = (lo2 + hi2) >> 1; if (batch[mid] < g + 1) lo2 = mid + 1; else hi2 = mid; }
    const int end = lo2;

    float acc = 0.f;
    for (int i = start + half; i < end; i += 2)
        acc += x[(size_t)i * HDIM + feat];
    acc += __shfl_xor(acc, 32);
    if (half == 0) {
        float cnt = (float)(end - start);
        out[(size_t)g * HDIM + feat] = acc / fmaxf(cnt, 1.f);
    }
}

// ---------------- Launch ----------------

extern "C" void kernel_launch(void* const* d_in, const int* in_sizes, int n_in,
                              void* d_out, int out_size, void* d_ws, size_t ws_size,
                              hipStream_t stream) {
    const float* x          = (const float*)d_in[0];
    const int*   edge_index = (const int*)d_in[1];
    const int*   batch      = (const int*)d_in[2];

    const int N = in_sizes[2];              // 100000
    const int E = in_sizes[1] / 2;          // 1600000
    const int G = out_size / HDIM;          // 2048
    const int B = (N + NPB - 1) / NPB;      // 782 buckets
    const int NBLK = (E + CHUNK - 1) / CHUNK;
    const int ntiles = (N + 63) / 64;

    const int* srcs = edge_index;
    const int* dsts = edge_index + E;

    // workspace layout (16B-aligned offsets)
    char* p = (char*)d_ws;
    __half* h     = (__half*)p; p += (size_t)N * HDIM * sizeof(__half);
    float* xbuf   = (float*)p; p += (size_t)N * HDIM * sizeof(float);
    int*   rowptr = (int*)p;   p += (size_t)(N + 1) * sizeof(int);
    p += 16 - ((size_t)p & 15);
    int*   csrsrc = (int*)p;   p += (size_t)E * sizeof(int);
    int*   pairs  = (int*)p;   p += (size_t)E * sizeof(int);
    int*   perm   = (int*)p;   p += (size_t)N * sizeof(int);
    int*   cnt2D  = (int*)p;   p += (size_t)NBLK * B * sizeof(int);
    int*   off2D  = (int*)p;   p += (size_t)NBLK * B * sizeof(int);
    int*   bcnt   = (int*)p;   p += (size_t)B * sizeof(int);
    int*   bstart = (int*)p;   p += (size_t)(B + 1) * sizeof(int);
    int*   dhist  = (int*)p;   p += (size_t)DBINS * sizeof(int);
    int*   dcur   = (int*)p;   p += (size_t)DBINS * sizeof(int);

    // ---- CSR build + degree-sort perm (once; same edges all 4 layers) ----
    chunk_hist  <<<NBLK, 256, 0, stream>>>(dsts, E, B, cnt2D);
    chunk_scan  <<<B, 256, 0, stream>>>(cnt2D, NBLK, B, off2D, bcnt);
    bucket_scan <<<1, 1024, 0, stream>>>(bcnt, B, E, bstart, rowptr, N);
    pair_scatter2<<<NBLK, 256, 0, stream>>>(srcs, dsts, E, B, off2D, bstart, pairs);
    bucket_sort <<<B, 256, 0, stream>>>(pairs, bstart, rowptr, csrsrc, N);
    hipMemsetAsync(dhist, 0, DBINS * sizeof(int), stream);
    deg_hist    <<<(N + 255) / 256, 256, 0, stream>>>(rowptr, N, dhist);
    deg_scan    <<<1, DBINS, 0, stream>>>(dhist, dcur);
    deg_scatter <<<(N + 255) / 256, 256, 0, stream>>>(rowptr, N, dcur, perm);

    const int aggGrid = (N * 4 + 255) / 256;

    // ---- 4 GAT layers ----
    for (int l = 0; l < 4; l++) {
        const float* W   = (const float*)d_in[3 + 4 * l];
        const float* a_s = (const float*)d_in[4 + 4 * l];
        const float* a_d = (const float*)d_in[5 + 4 * l];
        const float* bb  = (const float*)d_in[6 + 4 * l];

        if (l == 0) gemm_mfma<IN_DIM><<<ntiles, 256, 0, stream>>>(x, W, h, N);
        else        gemm_mfma<HDIM>  <<<ntiles, 256, 0, stream>>>(xbuf, W, h, N);

        agg6<<<aggGrid, 256, 0, stream>>>(h, rowptr, csrsrc, perm, a_s, a_d, bb, xbuf, N);
    }

    // ---- global mean pool: one wave per graph ----
    pool_graph<<<(G * 64 + 255) / 256, 256, 0, stream>>>(xbuf, batch, (float*)d_out, N, G);
}

// Round 13
// 348.033 us; speedup vs baseline: 2.3559x; 2.3559x over previous
//
#include <hip/hip_runtime.h>
#include <hip/hip_fp16.h>

#define HDIM 32
#define IN_DIM 128
#define NEG_SLOPE 0.2f
#define NPB 128            // nodes per coarse bucket (power of 2)
#define NPB_SHIFT 7
#define MAXB 1024          // max buckets (B = ceil(N/128) = 782)
#define CHUNK 8192         // edges per chunk block
#define CAP 4096           // max records per bucket for LDS sort fast path
#define DBINS 128          // degree bins for load-balance sort (clamp)
#define NCHUNK 256         // nodes per chunk for degree sort

typedef _Float16 half8  __attribute__((ext_vector_type(8)));
typedef _Float16 half4v __attribute__((ext_vector_type(4)));
typedef float    floatx4 __attribute__((ext_vector_type(4)));

__device__ __forceinline__ float leaky(float e) {
    return (e >= 0.f) ? e : NEG_SLOPE * e;
}

__device__ __forceinline__ float2 h2f(unsigned int u) {
    __half2 h = *reinterpret_cast<__half2*>(&u);
    return __half22float2(h);
}

// ------------- MFMA GEMM: h = x@W fp16 out -------------

template<int K>
__global__ __launch_bounds__(256) void gemm_mfma(
    const float* __restrict__ x, const float* __restrict__ W,
    __half* __restrict__ h, int N)
{
    constexpr int KP = K + 8;                 // +8 halves pad -> 2-way conflicts only
    __shared__ _Float16 xs[64 * KP];
    __shared__ _Float16 Wt[32 * KP];          // Wt[n][k] = W[k][n]
    const int tid = threadIdx.x;
    for (int i = tid; i < K * 32; i += 256) {
        int k = i >> 5, n = i & 31;
        Wt[n * KP + k] = (_Float16)W[i];
    }
    const int lane = tid & 63;
    const int wave = tid >> 6;                // 0..3
    const int m16  = lane & 15;
    const int quad = lane >> 4;               // 0..3

    const int ntiles = (N + 63) >> 6;
    for (int tile = blockIdx.x; tile < ntiles; tile += gridDim.x) {
        const int row0 = tile << 6;
        __syncthreads();
        for (int i = tid; i < 64 * (K / 4); i += 256) {
            int r  = i / (K / 4);
            int c4 = i % (K / 4);
            float4 v = (row0 + r < N) ? ((const float4*)x)[(size_t)(row0 + r) * (K / 4) + c4]
                                      : make_float4(0.f, 0.f, 0.f, 0.f);
            half4v hv = { (_Float16)v.x, (_Float16)v.y, (_Float16)v.z, (_Float16)v.w };
            *(half4v*)&xs[r * KP + c4 * 4] = hv;
        }
        __syncthreads();
        floatx4 acc0 = {0.f, 0.f, 0.f, 0.f}, acc1 = {0.f, 0.f, 0.f, 0.f};
        const int rbase = wave * 16;
        #pragma unroll
        for (int kt = 0; kt < K / 32; kt++) {
            half8 a  = *(half8*)&xs[(rbase + m16) * KP + kt * 32 + quad * 8];
            half8 b0 = *(half8*)&Wt[m16 * KP + kt * 32 + quad * 8];
            half8 b1 = *(half8*)&Wt[(m16 + 16) * KP + kt * 32 + quad * 8];
            acc0 = __builtin_amdgcn_mfma_f32_16x16x32_f16(a, b0, acc0, 0, 0, 0);
            acc1 = __builtin_amdgcn_mfma_f32_16x16x32_f16(a, b1, acc1, 0, 0, 0);
        }
        #pragma unroll
        for (int r = 0; r < 4; r++) {
            int row = row0 + rbase + quad * 4 + r;
            if (row < N) {
                h[(size_t)row * HDIM + m16]      = __float2half(acc0[r]);
                h[(size_t)row * HDIM + m16 + 16] = __float2half(acc1[r]);
            }
        }
    }
}

// ---------------- Two-level CSR build (once per call) ----------------

__global__ __launch_bounds__(256) void chunk_hist(
    const int* __restrict__ dsts, int E, int B, int* __restrict__ cnt2D)
{
    __shared__ int hist[MAXB];
    const int blk = blockIdx.x;
    for (int i = threadIdx.x; i < B; i += 256) hist[i] = 0;
    __syncthreads();
    const int e0 = blk * CHUNK;
    for (int i = threadIdx.x; i < CHUNK; i += 256) {
        int e = e0 + i;
        if (e < E) atomicAdd(&hist[dsts[e] >> NPB_SHIFT], 1);
    }
    __syncthreads();
    for (int i = threadIdx.x; i < B; i += 256) cnt2D[(size_t)blk * B + i] = hist[i];
}

__global__ __launch_bounds__(256) void chunk_scan(
    const int* __restrict__ cnt2D, int NBLK, int B,
    int* __restrict__ off2D, int* __restrict__ bcnt)
{
    __shared__ int s[256];
    const int b = blockIdx.x, t = threadIdx.x;
    int v = (t < NBLK) ? cnt2D[(size_t)t * B + b] : 0;
    s[t] = v;
    __syncthreads();
    for (int off = 1; off < 256; off <<= 1) {
        int add = (t >= off) ? s[t - off] : 0;
        __syncthreads();
        s[t] += add;
        __syncthreads();
    }
    if (t < NBLK) off2D[(size_t)t * B + b] = s[t] - v;
    if (t == 255) bcnt[b] = s[255];
}

__global__ __launch_bounds__(1024) void bucket_scan(
    const int* __restrict__ bcnt, int B, int E,
    int* __restrict__ bstart, int* __restrict__ rowptr, int N)
{
    __shared__ int s[1024];
    const int t = threadIdx.x;
    int v = (t < B) ? bcnt[t] : 0;
    s[t] = v;
    __syncthreads();
    for (int off = 1; off < 1024; off <<= 1) {
        int add = (t >= off) ? s[t - off] : 0;
        __syncthreads();
        s[t] += add;
        __syncthreads();
    }
    if (t < B) bstart[t] = s[t] - v;
    if (t == 0) { bstart[B] = E; rowptr[N] = E; }
}

__global__ __launch_bounds__(256) void pair_scatter2(
    const int* __restrict__ srcs, const int* __restrict__ dsts, int E, int B,
    const int* __restrict__ off2D, const int* __restrict__ bstart,
    int* __restrict__ pairs)
{
    __shared__ int cur[MAXB];
    const int blk = blockIdx.x;
    for (int i = threadIdx.x; i < B; i += 256)
        cur[i] = bstart[i] + off2D[(size_t)blk * B + i];
    __syncthreads();
    const int e0 = blk * CHUNK;
    for (int i = threadIdx.x; i < CHUNK; i += 256) {
        int e = e0 + i;
        if (e < E) {
            int s = srcs[e], d = dsts[e];
            int pos = atomicAdd(&cur[d >> NPB_SHIFT], 1);
            pairs[pos] = (s << NPB_SHIFT) | (d & (NPB - 1));
        }
    }
}

__global__ __launch_bounds__(256) void bucket_sort(
    const int* __restrict__ pairs, const int* __restrict__ bstart,
    int* __restrict__ rowptr, int* __restrict__ csrsrc, int N)
{
    __shared__ int ldeg[NPB];
    __shared__ int lex[NPB];
    __shared__ int recs[CAP];
    __shared__ int sorted[CAP];
    const int b = blockIdx.x, t = threadIdx.x;
    const int p0 = bstart[b], p1 = bstart[b + 1];
    const int cnt = p1 - p0;
    if (t < NPB) ldeg[t] = 0;
    __syncthreads();
    for (int i = t; i < cnt; i += 256) {
        int r = pairs[p0 + i];
        atomicAdd(&ldeg[r & (NPB - 1)], 1);
        if (i < CAP) recs[i] = r;
    }
    __syncthreads();
    if (t < NPB) lex[t] = ldeg[t];
    __syncthreads();
    for (int off = 1; off < NPB; off <<= 1) {
        int add = (t >= off && t < NPB) ? lex[t - off] : 0;
        __syncthreads();
        if (t < NPB) lex[t] += add;
        __syncthreads();
    }
    const int node0 = b * NPB;
    if (t < NPB) {
        int excl = lex[t] - ldeg[t];
        if (node0 + t < N) rowptr[node0 + t] = p0 + excl;
        ldeg[t] = excl;
    }
    __syncthreads();
    if (cnt <= CAP) {
        for (int i = t; i < cnt; i += 256) {
            int r = recs[i];
            int pos = atomicAdd(&ldeg[r & (NPB - 1)], 1);
            sorted[pos] = r >> NPB_SHIFT;
        }
        __syncthreads();
        for (int i = t; i < cnt; i += 256) csrsrc[p0 + i] = sorted[i];
    } else {
        for (int i = t; i < cnt; i += 256) {
            int r = pairs[p0 + i];
            int pos = atomicAdd(&ldeg[r & (NPB - 1)], 1);
            csrsrc[p0 + pos] = r >> NPB_SHIFT;
        }
    }
}

// ------ Degree-sort perm: two-level counting sort, LDS cursors only --------

__global__ __launch_bounds__(256) void deg_hist2(
    const int* __restrict__ rowptr, int N, int* __restrict__ dcnt2D)
{
    __shared__ int hist[DBINS];
    const int blk = blockIdx.x;
    if (threadIdx.x < DBINS) hist[threadIdx.x] = 0;
    __syncthreads();
    int i = blk * NCHUNK + threadIdx.x;
    if (i < N) {
        int d = rowptr[i + 1] - rowptr[i];
        if (d > DBINS - 1) d = DBINS - 1;
        atomicAdd(&hist[d], 1);              // LDS atomic, per-block
    }
    __syncthreads();
    if (threadIdx.x < DBINS) dcnt2D[(size_t)blk * DBINS + threadIdx.x] = hist[threadIdx.x];
}

// per-bin exclusive scan over chunks (grid = DBINS)
__global__ __launch_bounds__(512) void deg_chunkscan(
    const int* __restrict__ dcnt2D, int NB2,
    int* __restrict__ doff2D, int* __restrict__ dtot)
{
    __shared__ int s[512];
    const int bin = blockIdx.x, t = threadIdx.x;
    int v = (t < NB2) ? dcnt2D[(size_t)t * DBINS + bin] : 0;
    s[t] = v;
    __syncthreads();
    for (int off = 1; off < 512; off <<= 1) {
        int add = (t >= off) ? s[t - off] : 0;
        __syncthreads();
        s[t] += add;
        __syncthreads();
    }
    if (t < NB2) doff2D[(size_t)t * DBINS + bin] = s[t] - v;
    if (t == 511) dtot[bin] = s[511];
}

__global__ __launch_bounds__(DBINS) void deg_binscan(
    const int* __restrict__ dtot, int* __restrict__ dstart)
{
    __shared__ int s[DBINS];
    int t = threadIdx.x;
    int v = dtot[t];
    s[t] = v;
    __syncthreads();
    for (int off = 1; off < DBINS; off <<= 1) {
        int add = (t >= off) ? s[t - off] : 0;
        __syncthreads();
        s[t] += add;
        __syncthreads();
    }
    dstart[t] = s[t] - v;
}

__global__ __launch_bounds__(256) void deg_scatter2(
    const int* __restrict__ rowptr, int N,
    const int* __restrict__ doff2D, const int* __restrict__ dstart,
    int* __restrict__ perm)
{
    __shared__ int cur[DBINS];
    const int blk = blockIdx.x;
    if (threadIdx.x < DBINS)
        cur[threadIdx.x] = dstart[threadIdx.x] + doff2D[(size_t)blk * DBINS + threadIdx.x];
    __syncthreads();
    int i = blk * NCHUNK + threadIdx.x;
    if (i < N) {
        int d = rowptr[i + 1] - rowptr[i];
        if (d > DBINS - 1) d = DBINS - 1;
        int pos = atomicAdd(&cur[d], 1);     // LDS atomic, per-block
        perm[pos] = i;
    }
}

// -------- Aggregation: 4 lanes/node, degree-sorted perm, in-register es/ed --

__global__ __launch_bounds__(256) void agg6(
    const __half* __restrict__ h,
    const int* __restrict__ rowptr, const int* __restrict__ csrsrc,
    const int* __restrict__ perm,
    const float* __restrict__ a_s, const float* __restrict__ a_d,
    const float* __restrict__ b, float* __restrict__ out, int N)
{
    const int gid = blockIdx.x * 256 + threadIdx.x;
    const int gi  = gid >> 2;
    const int l   = threadIdx.x & 3;
    if (gi >= N) return;
    const int node = perm[gi];

    const int e0 = rowptr[node];
    const int e1 = rowptr[node + 1];
    const uint4* __restrict__ h16 = (const uint4*)h;

    float asf[8], adf[8];
    #pragma unroll
    for (int i = 0; i < 8; i++) { asf[i] = a_s[l * 8 + i]; adf[i] = a_d[l * 8 + i]; }

    uint4 uself = h16[(size_t)node * 4 + l];
    float2 g0 = h2f(uself.x), g1 = h2f(uself.y), g2 = h2f(uself.z), g3 = h2f(uself.w);
    float dsl = asf[0]*g0.x + asf[1]*g0.y + asf[2]*g1.x + asf[3]*g1.y
              + asf[4]*g2.x + asf[5]*g2.y + asf[6]*g3.x + asf[7]*g3.y;
    float ddl = adf[0]*g0.x + adf[1]*g0.y + adf[2]*g1.x + adf[3]*g1.y
              + adf[4]*g2.x + adf[5]*g2.y + adf[6]*g3.x + adf[7]*g3.y;
    dsl += __shfl_xor(dsl, 1); dsl += __shfl_xor(dsl, 2);
    ddl += __shfl_xor(ddl, 1); ddl += __shfl_xor(ddl, 2);
    const float edi = ddl;

    float a0=0.f,a1=0.f,a2=0.f,a3=0.f,a4=0.f,a5=0.f,a6=0.f,a7=0.f,den=0.f;

    int e = e0;
    for (; e + 8 <= e1; e += 8) {
        int s[8]; uint4 u[8];
        #pragma unroll
        for (int j = 0; j < 8; j++) s[j] = csrsrc[e + j];
        #pragma unroll
        for (int j = 0; j < 8; j++) u[j] = h16[(size_t)s[j] * 4 + l];
        #pragma unroll
        for (int j = 0; j < 8; j++) {
            float2 f0 = h2f(u[j].x), f1 = h2f(u[j].y), f2 = h2f(u[j].z), f3 = h2f(u[j].w);
            float dot = asf[0]*f0.x + asf[1]*f0.y + asf[2]*f1.x + asf[3]*f1.y
                      + asf[4]*f2.x + asf[5]*f2.y + asf[6]*f3.x + asf[7]*f3.y;
            dot += __shfl_xor(dot, 1);
            dot += __shfl_xor(dot, 2);
            float w = __expf(leaky(dot + edi));
            den += w;
            a0 += w*f0.x; a1 += w*f0.y; a2 += w*f1.x; a3 += w*f1.y;
            a4 += w*f2.x; a5 += w*f2.y; a6 += w*f3.x; a7 += w*f3.y;
        }
    }
    for (; e < e1; e++) {
        int s = csrsrc[e];
        uint4 u = h16[(size_t)s * 4 + l];
        float2 f0 = h2f(u.x), f1 = h2f(u.y), f2 = h2f(u.z), f3 = h2f(u.w);
        float dot = asf[0]*f0.x + asf[1]*f0.y + asf[2]*f1.x + asf[3]*f1.y
                  + asf[4]*f2.x + asf[5]*f2.y + asf[6]*f3.x + asf[7]*f3.y;
        dot += __shfl_xor(dot, 1);
        dot += __shfl_xor(dot, 2);
        float w = __expf(leaky(dot + edi));
        den += w;
        a0 += w*f0.x; a1 += w*f0.y; a2 += w*f1.x; a3 += w*f1.y;
        a4 += w*f2.x; a5 += w*f2.y; a6 += w*f3.x; a7 += w*f3.y;
    }
    {   // self-loop (row already in registers)
        float w = __expf(leaky(dsl + edi));
        den += w;
        a0 += w*g0.x; a1 += w*g0.y; a2 += w*g1.x; a3 += w*g1.y;
        a4 += w*g2.x; a5 += w*g2.y; a6 += w*g3.x; a7 += w*g3.y;
    }

    const float4* b4 = (const float4*)b;
    float4 bv0 = b4[2*l], bv1 = b4[2*l + 1];
    float inv = 1.f / den;
    float4 o0, o1;
    o0.x = a0*inv + bv0.x; o0.y = a1*inv + bv0.y; o0.z = a2*inv + bv0.z; o0.w = a3*inv + bv0.w;
    o1.x = a4*inv + bv1.x; o1.y = a5*inv + bv1.y; o1.z = a6*inv + bv1.z; o1.w = a7*inv + bv1.w;
    ((float4*)out)[(size_t)node*8 + 2*l]     = o0;
    ((float4*)out)[(size_t)node*8 + 2*l + 1] = o1;
}

// -------- Pool: one 64-lane wave per graph (batch sorted, binary search) ---

__global__ __launch_bounds__(256) void pool_graph(
    const float* __restrict__ x, const int* __restrict__ batch,
    float* __restrict__ out, int N, int G)
{
    const int g = (blockIdx.x * 256 + threadIdx.x) >> 6;   // wave id = graph id
    if (g >= G) return;
    const int lane = threadIdx.x & 63;
    const int feat = lane & 31;
    const int half = lane >> 5;

    int lo = 0, hi = N;
    while (lo < hi) { int mid = (lo + hi) >> 1; if (batch[mid] < g) lo = mid + 1; else hi = mid; }
    const int start = lo;
    int lo2 = start, hi2 = N;
    while (lo2 < hi2) { int mid = (lo2 + hi2) >> 1; if (batch[mid] < g + 1) lo2 = mid + 1; else hi2 = mid; }
    const int end = lo2;

    float acc = 0.f;
    for (int i = start + half; i < end; i += 2)
        acc += x[(size_t)i * HDIM + feat];
    acc += __shfl_xor(acc, 32);
    if (half == 0) {
        float cnt = (float)(end - start);
        out[(size_t)g * HDIM + feat] = acc / fmaxf(cnt, 1.f);
    }
}

// ---------------- Launch ----------------

extern "C" void kernel_launch(void* const* d_in, const int* in_sizes, int n_in,
                              void* d_out, int out_size, void* d_ws, size_t ws_size,
                              hipStream_t stream) {
    const float* x          = (const float*)d_in[0];
    const int*   edge_index = (const int*)d_in[1];
    const int*   batch      = (const int*)d_in[2];

    const int N = in_sizes[2];              // 100000
    const int E = in_sizes[1] / 2;          // 1600000
    const int G = out_size / HDIM;          // 2048
    const int B = (N + NPB - 1) / NPB;      // 782 buckets
    const int NBLK = (E + CHUNK - 1) / CHUNK;
    const int NB2  = (N + NCHUNK - 1) / NCHUNK;  // 391 (<=512 for scan)
    const int ntiles = (N + 63) / 64;

    const int* srcs = edge_index;
    const int* dsts = edge_index + E;

    // workspace layout (16B-aligned offsets)
    char* p = (char*)d_ws;
    __half* h     = (__half*)p; p += (size_t)N * HDIM * sizeof(__half);
    float* xbuf   = (float*)p; p += (size_t)N * HDIM * sizeof(float);
    int*   rowptr = (int*)p;   p += (size_t)(N + 1) * sizeof(int);
    p += 16 - ((size_t)p & 15);
    int*   csrsrc = (int*)p;   p += (size_t)E * sizeof(int);
    int*   pairs  = (int*)p;   p += (size_t)E * sizeof(int);
    int*   perm   = (int*)p;   p += (size_t)N * sizeof(int);
    int*   cnt2D  = (int*)p;   p += (size_t)NBLK * B * sizeof(int);
    int*   off2D  = (int*)p;   p += (size_t)NBLK * B * sizeof(int);
    int*   bcnt   = (int*)p;   p += (size_t)B * sizeof(int);
    int*   bstart = (int*)p;   p += (size_t)(B + 1) * sizeof(int);
    int*   dcnt2D = (int*)p;   p += (size_t)NB2 * DBINS * sizeof(int);
    int*   doff2D = (int*)p;   p += (size_t)NB2 * DBINS * sizeof(int);
    int*   dtot   = (int*)p;   p += (size_t)DBINS * sizeof(int);
    int*   dstart = (int*)p;   p += (size_t)DBINS * sizeof(int);

    // ---- CSR build + degree-sort perm (once; same edges all 4 layers) ----
    chunk_hist  <<<NBLK, 256, 0, stream>>>(dsts, E, B, cnt2D);
    chunk_scan  <<<B, 256, 0, stream>>>(cnt2D, NBLK, B, off2D, bcnt);
    bucket_scan <<<1, 1024, 0, stream>>>(bcnt, B, E, bstart, rowptr, N);
    pair_scatter2<<<NBLK, 256, 0, stream>>>(srcs, dsts, E, B, off2D, bstart, pairs);
    bucket_sort <<<B, 256, 0, stream>>>(pairs, bstart, rowptr, csrsrc, N);
    deg_hist2   <<<NB2, 256, 0, stream>>>(rowptr, N, dcnt2D);
    deg_chunkscan<<<DBINS, 512, 0, stream>>>(dcnt2D, NB2, doff2D, dtot);
    deg_binscan <<<1, DBINS, 0, stream>>>(dtot, dstart);
    deg_scatter2<<<NB2, 256, 0, stream>>>(rowptr, N, doff2D, dstart, perm);

    const int aggGrid = (N * 4 + 255) / 256;

    // ---- 4 GAT layers ----
    for (int l = 0; l < 4; l++) {
        const float* W   = (const float*)d_in[3 + 4 * l];
        const float* a_s = (const float*)d_in[4 + 4 * l];
        const float* a_d = (const float*)d_in[5 + 4 * l];
        const float* bb  = (const float*)d_in[6 + 4 * l];

        if (l == 0) gemm_mfma<IN_DIM><<<ntiles, 256, 0, stream>>>(x, W, h, N);
        else        gemm_mfma<HDIM>  <<<ntiles, 256, 0, stream>>>(xbuf, W, h, N);

        agg6<<<aggGrid, 256, 0, stream>>>(h, rowptr, csrsrc, perm, a_s, a_d, bb, xbuf, N);
    }

    // ---- global mean pool: one wave per graph ----
    pool_graph<<<(G * 64 + 255) / 256, 256, 0, stream>>>(xbuf, batch, (float*)d_out, N, G);
}

// Round 14
// 331.018 us; speedup vs baseline: 2.4770x; 1.0514x over previous
//
#include <hip/hip_runtime.h>
#include <hip/hip_fp16.h>

#define HDIM 32
#define IN_DIM 128
#define NEG_SLOPE 0.2f
#define NPB 128            // nodes per coarse bucket (power of 2)
#define NPB_SHIFT 7
#define MAXB 1024          // max buckets (B = ceil(N/128) = 782)
#define CHUNK 8192         // edges per chunk block
#define CAP 4096           // max records per bucket for LDS sort fast path

typedef _Float16 half8  __attribute__((ext_vector_type(8)));
typedef _Float16 half4v __attribute__((ext_vector_type(4)));
typedef float    floatx4 __attribute__((ext_vector_type(4)));
typedef float    floatx2 __attribute__((ext_vector_type(2)));

__device__ __forceinline__ float leaky(float e) {
    return (e >= 0.f) ? e : NEG_SLOPE * e;
}

// ------------- MFMA GEMM: h = x@W, fp8-e4m3 packed out + exact fp32 es/ed --

template<int K>
__global__ __launch_bounds__(256) void gemm_mfma(
    const float* __restrict__ x, const float* __restrict__ W,
    const float* __restrict__ a_s, const float* __restrict__ a_d,
    uint2* __restrict__ h8, float* __restrict__ es, float* __restrict__ ed, int N)
{
    constexpr int KP = K + 8;                 // +8 halves pad -> 2-way conflicts only
    __shared__ _Float16 xs[64 * KP];
    __shared__ _Float16 Wt[32 * KP];          // Wt[n][k] = W[k][n]
    __shared__ float stage[64 * 33];          // fp32 results for fp8 pack (33-stride)
    const int tid = threadIdx.x;
    for (int i = tid; i < K * 32; i += 256) {
        int k = i >> 5, n = i & 31;
        Wt[n * KP + k] = (_Float16)W[i];
    }
    const int lane = tid & 63;
    const int wave = tid >> 6;                // 0..3
    const int m16  = lane & 15;
    const int quad = lane >> 4;               // 0..3
    const float as0 = a_s[m16], as1 = a_s[m16 + 16];
    const float ad0 = a_d[m16], ad1 = a_d[m16 + 16];

    const int ntiles = (N + 63) >> 6;
    for (int tile = blockIdx.x; tile < ntiles; tile += gridDim.x) {
        const int row0 = tile << 6;
        __syncthreads();
        for (int i = tid; i < 64 * (K / 4); i += 256) {
            int r  = i / (K / 4);
            int c4 = i % (K / 4);
            float4 v = (row0 + r < N) ? ((const float4*)x)[(size_t)(row0 + r) * (K / 4) + c4]
                                      : make_float4(0.f, 0.f, 0.f, 0.f);
            half4v hv = { (_Float16)v.x, (_Float16)v.y, (_Float16)v.z, (_Float16)v.w };
            *(half4v*)&xs[r * KP + c4 * 4] = hv;
        }
        __syncthreads();
        floatx4 acc0 = {0.f, 0.f, 0.f, 0.f}, acc1 = {0.f, 0.f, 0.f, 0.f};
        const int rbase = wave * 16;
        #pragma unroll
        for (int kt = 0; kt < K / 32; kt++) {
            half8 a  = *(half8*)&xs[(rbase + m16) * KP + kt * 32 + quad * 8];
            half8 b0 = *(half8*)&Wt[m16 * KP + kt * 32 + quad * 8];
            half8 b1 = *(half8*)&Wt[(m16 + 16) * KP + kt * 32 + quad * 8];
            acc0 = __builtin_amdgcn_mfma_f32_16x16x32_f16(a, b0, acc0, 0, 0, 0);
            acc1 = __builtin_amdgcn_mfma_f32_16x16x32_f16(a, b1, acc1, 0, 0, 0);
        }
        #pragma unroll
        for (int r = 0; r < 4; r++) {
            const int lr = rbase + quad * 4 + r;
            int row = row0 + lr;
            float c0 = acc0[r], c1 = acc1[r];
            stage[lr * 33 + m16]      = c0;
            stage[lr * 33 + m16 + 16] = c1;
            float ps = c0 * as0 + c1 * as1;
            float pd = c0 * ad0 + c1 * ad1;
            #pragma unroll
            for (int m = 8; m >= 1; m >>= 1) { ps += __shfl_xor(ps, m); pd += __shfl_xor(pd, m); }
            if (row < N && m16 == 0) { es[row] = ps; ed[row] = pd; }
        }
        __syncthreads();
        {   // pack 64 rows x 32 cols fp32 -> fp8, coalesced uint2 stores
            int r = tid >> 2, seg = tid & 3;
            int row = row0 + r;
            if (row < N) {
                const float* sp = &stage[r * 33 + seg * 8];
                unsigned int u0, u1;
                u0 = __builtin_amdgcn_cvt_pk_fp8_f32(sp[0], sp[1], 0,  false);
                u0 = __builtin_amdgcn_cvt_pk_fp8_f32(sp[2], sp[3], u0, true);
                u1 = __builtin_amdgcn_cvt_pk_fp8_f32(sp[4], sp[5], 0,  false);
                u1 = __builtin_amdgcn_cvt_pk_fp8_f32(sp[6], sp[7], u1, true);
                h8[(size_t)row * 4 + seg] = make_uint2(u0, u1);
            }
        }
    }
}

// ---------------- Two-level CSR build (once per call) ----------------

__global__ __launch_bounds__(256) void chunk_hist(
    const int* __restrict__ dsts, int E, int B, int* __restrict__ cnt2D)
{
    __shared__ int hist[MAXB];
    const int blk = blockIdx.x;
    for (int i = threadIdx.x; i < B; i += 256) hist[i] = 0;
    __syncthreads();
    const int e0 = blk * CHUNK;
    for (int i = threadIdx.x; i < CHUNK; i += 256) {
        int e = e0 + i;
        if (e < E) atomicAdd(&hist[dsts[e] >> NPB_SHIFT], 1);
    }
    __syncthreads();
    for (int i = threadIdx.x; i < B; i += 256) cnt2D[(size_t)blk * B + i] = hist[i];
}

__global__ __launch_bounds__(256) void chunk_scan(
    const int* __restrict__ cnt2D, int NBLK, int B,
    int* __restrict__ off2D, int* __restrict__ bcnt)
{
    __shared__ int s[256];
    const int b = blockIdx.x, t = threadIdx.x;
    int v = (t < NBLK) ? cnt2D[(size_t)t * B + b] : 0;
    s[t] = v;
    __syncthreads();
    for (int off = 1; off < 256; off <<= 1) {
        int add = (t >= off) ? s[t - off] : 0;
        __syncthreads();
        s[t] += add;
        __syncthreads();
    }
    if (t < NBLK) off2D[(size_t)t * B + b] = s[t] - v;
    if (t == 255) bcnt[b] = s[255];
}

__global__ __launch_bounds__(1024) void bucket_scan(
    const int* __restrict__ bcnt, int B, int E,
    int* __restrict__ bstart, int* __restrict__ rowptr, int N)
{
    __shared__ int s[1024];
    const int t = threadIdx.x;
    int v = (t < B) ? bcnt[t] : 0;
    s[t] = v;
    __syncthreads();
    for (int off = 1; off < 1024; off <<= 1) {
        int add = (t >= off) ? s[t - off] : 0;
        __syncthreads();
        s[t] += add;
        __syncthreads();
    }
    if (t < B) bstart[t] = s[t] - v;
    if (t == 0) { bstart[B] = E; rowptr[N] = E; }
}

__global__ __launch_bounds__(256) void pair_scatter2(
    const int* __restrict__ srcs, const int* __restrict__ dsts, int E, int B,
    const int* __restrict__ off2D, const int* __restrict__ bstart,
    int* __restrict__ pairs)
{
    __shared__ int cur[MAXB];
    const int blk = blockIdx.x;
    for (int i = threadIdx.x; i < B; i += 256)
        cur[i] = bstart[i] + off2D[(size_t)blk * B + i];
    __syncthreads();
    const int e0 = blk * CHUNK;
    for (int i = threadIdx.x; i < CHUNK; i += 256) {
        int e = e0 + i;
        if (e < E) {
            int s = srcs[e], d = dsts[e];
            int pos = atomicAdd(&cur[d >> NPB_SHIFT], 1);
            pairs[pos] = (s << NPB_SHIFT) | (d & (NPB - 1));
        }
    }
}

__global__ __launch_bounds__(256) void bucket_sort(
    const int* __restrict__ pairs, const int* __restrict__ bstart,
    int* __restrict__ rowptr, int* __restrict__ csrsrc, int N)
{
    __shared__ int ldeg[NPB];
    __shared__ int lex[NPB];
    __shared__ int recs[CAP];
    __shared__ int sorted[CAP];
    const int b = blockIdx.x, t = threadIdx.x;
    const int p0 = bstart[b], p1 = bstart[b + 1];
    const int cnt = p1 - p0;
    if (t < NPB) ldeg[t] = 0;
    __syncthreads();
    for (int i = t; i < cnt; i += 256) {
        int r = pairs[p0 + i];
        atomicAdd(&ldeg[r & (NPB - 1)], 1);
        if (i < CAP) recs[i] = r;
    }
    __syncthreads();
    if (t < NPB) lex[t] = ldeg[t];
    __syncthreads();
    for (int off = 1; off < NPB; off <<= 1) {
        int add = (t >= off && t < NPB) ? lex[t - off] : 0;
        __syncthreads();
        if (t < NPB) lex[t] += add;
        __syncthreads();
    }
    const int node0 = b * NPB;
    if (t < NPB) {
        int excl = lex[t] - ldeg[t];
        if (node0 + t < N) rowptr[node0 + t] = p0 + excl;
        ldeg[t] = excl;
    }
    __syncthreads();
    if (cnt <= CAP) {
        for (int i = t; i < cnt; i += 256) {
            int r = recs[i];
            int pos = atomicAdd(&ldeg[r & (NPB - 1)], 1);
            sorted[pos] = r >> NPB_SHIFT;
        }
        __syncthreads();
        for (int i = t; i < cnt; i += 256) csrsrc[p0 + i] = sorted[i];
    } else {
        for (int i = t; i < cnt; i += 256) {
            int r = pairs[p0 + i];
            int pos = atomicAdd(&ldeg[r & (NPB - 1)], 1);
            csrsrc[p0 + pos] = r >> NPB_SHIFT;
        }
    }
}

// -------- Aggregation: 4 lanes/node, fp8 h gather (32 B/row), exact es/ed --

__global__ __launch_bounds__(256) void agg7(
    const uint2* __restrict__ h8, const float* __restrict__ es, const float* __restrict__ ed,
    const int* __restrict__ rowptr, const int* __restrict__ csrsrc,
    const float* __restrict__ b, float* __restrict__ out, int N)
{
    const int gid  = blockIdx.x * 256 + threadIdx.x;
    const int node = gid >> 2;
    const int l    = threadIdx.x & 3;
    if (node >= N) return;

    const int e0 = rowptr[node];
    const int e1 = rowptr[node + 1];
    const float edi = ed[node];

    float a0=0.f,a1=0.f,a2=0.f,a3=0.f,a4=0.f,a5=0.f,a6=0.f,a7=0.f,den=0.f;

    int e = e0;
    for (; e + 8 <= e1; e += 8) {
        int s[8]; float q[8]; uint2 u[8];
        #pragma unroll
        for (int j = 0; j < 8; j++) s[j] = csrsrc[e + j];
        #pragma unroll
        for (int j = 0; j < 8; j++) q[j] = es[s[j]];
        #pragma unroll
        for (int j = 0; j < 8; j++) u[j] = h8[(size_t)s[j] * 4 + l];
        #pragma unroll
        for (int j = 0; j < 8; j++) {
            floatx2 f0 = __builtin_amdgcn_cvt_pk_f32_fp8(u[j].x, false);
            floatx2 f1 = __builtin_amdgcn_cvt_pk_f32_fp8(u[j].x, true);
            floatx2 f2 = __builtin_amdgcn_cvt_pk_f32_fp8(u[j].y, false);
            floatx2 f3 = __builtin_amdgcn_cvt_pk_f32_fp8(u[j].y, true);
            float w = __expf(leaky(q[j] + edi));
            den += w;
            a0 += w*f0.x; a1 += w*f0.y; a2 += w*f1.x; a3 += w*f1.y;
            a4 += w*f2.x; a5 += w*f2.y; a6 += w*f3.x; a7 += w*f3.y;
        }
    }
    for (; e < e1; e++) {
        int s = csrsrc[e];
        float q = es[s];
        uint2 u = h8[(size_t)s * 4 + l];
        floatx2 f0 = __builtin_amdgcn_cvt_pk_f32_fp8(u.x, false);
        floatx2 f1 = __builtin_amdgcn_cvt_pk_f32_fp8(u.x, true);
        floatx2 f2 = __builtin_amdgcn_cvt_pk_f32_fp8(u.y, false);
        floatx2 f3 = __builtin_amdgcn_cvt_pk_f32_fp8(u.y, true);
        float w = __expf(leaky(q + edi));
        den += w;
        a0 += w*f0.x; a1 += w*f0.y; a2 += w*f1.x; a3 += w*f1.y;
        a4 += w*f2.x; a5 += w*f2.y; a6 += w*f3.x; a7 += w*f3.y;
    }
    {   // self-loop
        float w = __expf(leaky(es[node] + edi));
        uint2 u = h8[(size_t)node * 4 + l];
        floatx2 f0 = __builtin_amdgcn_cvt_pk_f32_fp8(u.x, false);
        floatx2 f1 = __builtin_amdgcn_cvt_pk_f32_fp8(u.x, true);
        floatx2 f2 = __builtin_amdgcn_cvt_pk_f32_fp8(u.y, false);
        floatx2 f3 = __builtin_amdgcn_cvt_pk_f32_fp8(u.y, true);
        den += w;
        a0 += w*f0.x; a1 += w*f0.y; a2 += w*f1.x; a3 += w*f1.y;
        a4 += w*f2.x; a5 += w*f2.y; a6 += w*f3.x; a7 += w*f3.y;
    }

    const float4* b4 = (const float4*)b;
    float4 bv0 = b4[2*l], bv1 = b4[2*l + 1];
    float inv = 1.f / den;
    float4 o0, o1;
    o0.x = a0*inv + bv0.x; o0.y = a1*inv + bv0.y; o0.z = a2*inv + bv0.z; o0.w = a3*inv + bv0.w;
    o1.x = a4*inv + bv1.x; o1.y = a5*inv + bv1.y; o1.z = a6*inv + bv1.z; o1.w = a7*inv + bv1.w;
    ((float4*)out)[(size_t)node*8 + 2*l]     = o0;
    ((float4*)out)[(size_t)node*8 + 2*l + 1] = o1;
}

// -------- Pool: one 64-lane wave per graph (batch sorted, binary search) ---

__global__ __launch_bounds__(256) void pool_graph(
    const float* __restrict__ x, const int* __restrict__ batch,
    float* __restrict__ out, int N, int G)
{
    const int g = (blockIdx.x * 256 + threadIdx.x) >> 6;   // wave id = graph id
    if (g >= G) return;
    const int lane = threadIdx.x & 63;
    const int feat = lane & 31;
    const int half = lane >> 5;

    int lo = 0, hi = N;
    while (lo < hi) { int mid = (lo + hi) >> 1; if (batch[mid] < g) lo = mid + 1; else hi = mid; }
    const int start = lo;
    int lo2 = start, hi2 = N;
    while (lo2 < hi2) { int mid = (lo2 + hi2) >> 1; if (batch[mid] < g + 1) lo2 = mid + 1; else hi2 = mid; }
    const int end = lo2;

    float acc = 0.f;
    for (int i = start + half; i < end; i += 2)
        acc += x[(size_t)i * HDIM + feat];
    acc += __shfl_xor(acc, 32);
    if (half == 0) {
        float cnt = (float)(end - start);
        out[(size_t)g * HDIM + feat] = acc / fmaxf(cnt, 1.f);
    }
}

// ---------------- Launch ----------------

extern "C" void kernel_launch(void* const* d_in, const int* in_sizes, int n_in,
                              void* d_out, int out_size, void* d_ws, size_t ws_size,
                              hipStream_t stream) {
    const float* x          = (const float*)d_in[0];
    const int*   edge_index = (const int*)d_in[1];
    const int*   batch      = (const int*)d_in[2];

    const int N = in_sizes[2];              // 100000
    const int E = in_sizes[1] / 2;          // 1600000
    const int G = out_size / HDIM;          // 2048
    const int B = (N + NPB - 1) / NPB;      // 782 buckets
    const int NBLK = (E + CHUNK - 1) / CHUNK;
    const int ntiles = (N + 63) / 64;

    const int* srcs = edge_index;
    const int* dsts = edge_index + E;

    // workspace layout (16B-aligned offsets)
    char* p = (char*)d_ws;
    uint2* h8     = (uint2*)p; p += (size_t)N * 4 * sizeof(uint2);  // fp8 rows, 32 B
    float* xbuf   = (float*)p; p += (size_t)N * HDIM * sizeof(float);
    float* es     = (float*)p; p += (size_t)N * sizeof(float);
    float* ed     = (float*)p; p += (size_t)N * sizeof(float);
    int*   rowptr = (int*)p;   p += (size_t)(N + 1) * sizeof(int);
    p += 16 - ((size_t)p & 15);
    int*   csrsrc = (int*)p;   p += (size_t)E * sizeof(int);
    int*   pairs  = (int*)p;   p += (size_t)E * sizeof(int);
    int*   cnt2D  = (int*)p;   p += (size_t)NBLK * B * sizeof(int);
    int*   off2D  = (int*)p;   p += (size_t)NBLK * B * sizeof(int);
    int*   bcnt   = (int*)p;   p += (size_t)B * sizeof(int);
    int*   bstart = (int*)p;   p += (size_t)(B + 1) * sizeof(int);

    // ---- CSR build (once; same edge set for all 4 layers) ----
    chunk_hist  <<<NBLK, 256, 0, stream>>>(dsts, E, B, cnt2D);
    chunk_scan  <<<B, 256, 0, stream>>>(cnt2D, NBLK, B, off2D, bcnt);
    bucket_scan <<<1, 1024, 0, stream>>>(bcnt, B, E, bstart, rowptr, N);
    pair_scatter2<<<NBLK, 256, 0, stream>>>(srcs, dsts, E, B, off2D, bstart, pairs);
    bucket_sort <<<B, 256, 0, stream>>>(pairs, bstart, rowptr, csrsrc, N);

    const int aggGrid = (N * 4 + 255) / 256;

    // ---- 4 GAT layers ----
    for (int l = 0; l < 4; l++) {
        const float* W   = (const float*)d_in[3 + 4 * l];
        const float* a_s = (const float*)d_in[4 + 4 * l];
        const float* a_d = (const float*)d_in[5 + 4 * l];
        const float* bb  = (const float*)d_in[6 + 4 * l];

        if (l == 0) gemm_mfma<IN_DIM><<<ntiles, 256, 0, stream>>>(x, W, a_s, a_d, h8, es, ed, N);
        else        gemm_mfma<HDIM>  <<<ntiles, 256, 0, stream>>>(xbuf, W, a_s, a_d, h8, es, ed, N);

        agg7<<<aggGrid, 256, 0, stream>>>(h8, es, ed, rowptr, csrsrc, bb, xbuf, N);
    }

    // ---- global mean pool: one wave per graph ----
    pool_graph<<<(G * 64 + 255) / 256, 256, 0, stream>>>(xbuf, batch, (float*)d_out, N, G);
}